// Round 3
// baseline (343.605 us; speedup 1.0000x reference)
//
#include <hip/hip_runtime.h>
#include <hip/hip_bf16.h>

// MinGRU: L=2 layers of  h_t = (1-z_t) h_{t-1} + z_t g(pre_t)
// R6: (a) gemm back to proven R3 geometry (128x64 tile, 4 waves, 2 blocks/CU)
//     + minimum 2-phase double-buffer prefetch with counted vmcnt(8)
//     (T3-lite, m248v2 +10%), keeping R5's coalesced h8 cv layout.
//     (b) dispatch fusion 9->5: single cast kernel; chunk-prefix scan folded
//     into scan_emit (hin buffer removed).
//     Accumulation order bit-identical to R3/R5.

#define L_ 2
#define B_ 8
#define S_ 2048
#define D_ 1024
#define H_ 1024
#define M_ (B_*S_)     // 16384
#define NC 32          // chunks per sequence
#define CL (S_/NC)     // 64 steps per chunk

typedef __bf16    bf16x8 __attribute__((ext_vector_type(8)));
typedef float     f32x4  __attribute__((ext_vector_type(4)));
typedef _Float16  h2     __attribute__((ext_vector_type(2)));
typedef _Float16  h8     __attribute__((ext_vector_type(8)));

__device__ __forceinline__ ushort f2bf(float f) {
    union { __hip_bfloat16 h; ushort u; } c;
    c.h = __float2bfloat16(f);   // RNE
    return c.u;
}

__device__ __forceinline__ void async16(const void* g, void* l) {
    __builtin_amdgcn_global_load_lds(
        (const __attribute__((address_space(1))) unsigned int*)g,
        (__attribute__((address_space(3))) unsigned int*)l, 16, 0, 0);
}

// Single fused cast: x (M*D f32->bf16) and, for the low i-range, Wz/Wh too.
__global__ __launch_bounds__(256) void cast_all(const float* __restrict__ x,
                                                const float* __restrict__ Wz,
                                                const float* __restrict__ Wh,
                                                ushort* __restrict__ xb,
                                                ushort* __restrict__ wzb,
                                                ushort* __restrict__ whb) {
    const int nw = L_*H_*D_/4;                       // 524288
    int i = blockIdx.x * 256 + threadIdx.x;          // grid covers M_*D_/4
    {
        float4 v = ((const float4*)x)[i];
        ushort4 o;
        o.x = f2bf(v.x); o.y = f2bf(v.y); o.z = f2bf(v.z); o.w = f2bf(v.w);
        ((ushort4*)xb)[i] = o;
    }
    if (i < nw) {
        float4 v = ((const float4*)Wz)[i];
        ushort4 o;
        o.x = f2bf(v.x); o.y = f2bf(v.y); o.z = f2bf(v.z); o.w = f2bf(v.w);
        ((ushort4*)wzb)[i] = o;
        float4 w = ((const float4*)Wh)[i];
        ushort4 p;
        p.x = f2bf(w.x); p.y = f2bf(w.y); p.z = f2bf(w.z); p.w = f2bf(w.w);
        ((ushort4*)whb)[i] = p;
    }
}

// LDS layout: row R = 64 ushorts (8 chunks of 16B); logical chunk c stored at
// physical chunk c ^ (R&7).  Offset in ushorts:
#define SWZ(R, c) (((R) << 6) + ((((c) ^ ((R) & 7))) << 3))
#define MFMA16 __builtin_amdgcn_mfma_f32_16x16x32_bf16
#define FENCE() asm volatile("" ::: "memory")

// Fused dual-GEMM: k = A@Wz^T+bz, pre = A@Wh^T+bh over a 128m x 64n tile.
// cv[(m>>2)*H + n] is a 16B h8: (c,v) pairs for m&3 = 0..3.
// LDS: 2 buffers x 16384 ushorts: As 128x64 @+0, Zs 64x64 @+8192, Hs @+12288.
// 2-phase pipeline: stage(t+1, nxt) issued before compute(t, cur); counted
// vmcnt(8) (8 stage instrs/wave in flight) -- never drain-0 in the loop.
__global__ __launch_bounds__(256) void gemm_fused(const ushort* __restrict__ A,
                                                  const ushort* __restrict__ Wz,
                                                  const ushort* __restrict__ Wh,
                                                  const float* __restrict__ bz,
                                                  const float* __restrict__ bh,
                                                  h2* __restrict__ cv,
                                                  float* __restrict__ Ac,
                                                  float* __restrict__ Bc)
{
    extern __shared__ __align__(16) ushort sm[];     // 64 KiB dynamic (2 bufs)

    const int t    = threadIdx.x;
    const int lane = t & 63;
    const int wave = t >> 6;                         // 0..3
    // XCD-aware swizzle (2048 blocks, %8==0 -> bijective): 16 blocks sharing an
    // A-tile get the same XCD L2.
    const int xcd = (int)blockIdx.x & 7;
    const int k8  = (int)blockIdx.x >> 3;            // 0..255
    const int nblk = k8 & 15;
    const int mblk = ((k8 >> 4) << 3) + xcd;         // 0..127
    const int m0 = mblk * 128;
    const int n0 = nblk * 64;
    const int wm = (wave >> 1) * 64;                 // 0 / 64
    const int wn = (wave & 1) * 32;                  // 0 / 32

    const int srow   = lane >> 3;                    // 0..7
    const int scol_g = (((lane & 7) ^ srow) << 3);   // swizzled source chunk

    f32x4 accz[4][2] = {};
    f32x4 acch[4][2] = {};
    const int lrow = lane & 15;
    const int lcq  = lane >> 4;                      // chunk sub-index 0..3

    // ---- staging macro: 8 async16 per wave into buffer at ushort offset bo --
    #define STAGE(kb, bo)                                                      \
        do {                                                                   \
            _Pragma("unroll")                                                  \
            for (int i_ = 0; i_ < 4; ++i_) {          /* A: 128 rows */        \
                int r_ = i_*32 + wave*8;                                       \
                async16(&A[(size_t)(m0 + r_ + srow)*D_ + (kb) + scol_g],       \
                        &sm[(bo) + r_*64]);                                    \
            }                                                                  \
            _Pragma("unroll")                                                  \
            for (int i_ = 0; i_ < 2; ++i_) {          /* Wz, Wh: 64 rows */    \
                int r_ = i_*32 + wave*8;                                       \
                async16(&Wz[(size_t)(n0 + r_ + srow)*D_ + (kb) + scol_g],      \
                        &sm[(bo) + 8192 + r_*64]);                             \
                async16(&Wh[(size_t)(n0 + r_ + srow)*D_ + (kb) + scol_g],      \
                        &sm[(bo) + 12288 + r_*64]);                            \
            }                                                                  \
        } while (0)

    STAGE(0, 0);                                     // prologue: tile 0 -> buf0

    #pragma unroll 2
    for (int tt = 0; tt < 16; ++tt) {
        const int cur = (tt & 1) << 14;              // *16384 ushorts
        const int nxt = cur ^ 16384;
        const int kbn = (tt < 15 ? tt + 1 : 15) << 6;  // tail re-stage (benign)
        STAGE(kbn, nxt);
        asm volatile("s_waitcnt vmcnt(8)" ::: "memory"); // tile tt landed
        __builtin_amdgcn_s_barrier();
        FENCE();
        #pragma unroll
        for (int kk = 0; kk < 64; kk += 32) {
            const int cq = (kk >> 3) + lcq;          // logical chunk 0..7
            bf16x8 af[4];
            #pragma unroll
            for (int mt = 0; mt < 4; ++mt) {
                int R = wm + mt*16 + lrow;
                uint4 u = *(const uint4*)&sm[cur + SWZ(R, cq)];
                af[mt] = __builtin_bit_cast(bf16x8, u);
            }
            #pragma unroll
            for (int nt = 0; nt < 2; ++nt) {
                int R = wn + nt*16 + lrow;
                uint4 uz = *(const uint4*)&sm[cur + 8192  + SWZ(R, cq)];
                uint4 uh = *(const uint4*)&sm[cur + 12288 + SWZ(R, cq)];
                bf16x8 zb = __builtin_bit_cast(bf16x8, uz);
                bf16x8 hb = __builtin_bit_cast(bf16x8, uh);
                #pragma unroll
                for (int mt = 0; mt < 4; ++mt) {
                    accz[mt][nt] = MFMA16(af[mt], zb, accz[mt][nt], 0, 0, 0);
                    acch[mt][nt] = MFMA16(af[mt], hb, acch[mt][nt], 0, 0, 0);
                }
            }
        }
        FENCE();
        __builtin_amdgcn_s_barrier();                // reads done before restage
    }

    asm volatile("s_waitcnt vmcnt(0)" ::: "memory"); // drain tail restage
    __syncthreads();                                 // LDS now reusable

    // ---- epilogue: nonlinearity + coalesced cv write + per-4-row affines ----
    float2* seg = (float2*)sm;                       // [32 segs][stride 65] float2
    const int colq = lane & 15;
    const int rowq = (lane >> 4) << 2;
    #pragma unroll
    for (int nt = 0; nt < 2; ++nt) {
        const int n = n0 + wn + nt*16 + colq;
        const float bzv = bz[n];
        const float bhv = bh[n];
        #pragma unroll
        for (int mt = 0; mt < 4; ++mt) {
            float a = 1.f, bb = 0.f;                 // affine over this lane's 4 rows
            h8 pk;
            #pragma unroll
            for (int r = 0; r < 4; ++r) {
                float kx = accz[mt][nt][r] + bzv;
                float p  = acch[mt][nt][r] + bhv;
                float e   = __expf(-fabsf(kx));
                float inv = 1.0f / (1.0f + e);
                float z   = (kx >= 0.f) ? inv     : e * inv;
                float c   = (kx >= 0.f) ? e * inv : inv;
                float g;
                if (p >= 0.f) g = p + 0.5f;
                else { float eg = __expf(p); g = eg / (1.0f + eg); }
                float v = z * g;
                pk[2*r]     = (_Float16)c;
                pk[2*r + 1] = (_Float16)v;
                bb = fmaf(c, bb, v);
                a *= c;
            }
            const int mb4 = (m0 + wm + mt*16 + rowq) >> 2;   // m&3 == r
            *(h8*)&cv[((size_t)mb4 * H_ + n) * 4] = pk;      // 16B coalesced
            const int sidx = (wm >> 2) + mt*4 + (rowq >> 2); // 0..31, time-ordered
            seg[sidx*65 + wn + nt*16 + colq] = make_float2(a, bb);
        }
    }
    __syncthreads();
    // two chunks of CL=64 per tile: segs 0..15 -> chunk 2*c0, segs 16..31 -> +1
    if (t < 128) {
        const int col  = t & 63;
        const int half = t >> 6;
        float a = 1.f, bb = 0.f;
        #pragma unroll
        for (int s = 0; s < 16; ++s) {
            float2 e2 = seg[(half*16 + s)*65 + col];
            bb = fmaf(e2.x, bb, e2.y);
            a *= e2.x;
        }
        const int b     = m0 >> 11;                  // S = 2048
        const int chunk = ((m0 >> 6) & (NC - 1)) + half;
        const int q = (b*NC + chunk)*H_ + n0 + col;
        Ac[q] = a; Bc[q] = bb;
    }
    #undef STAGE
}

// Fused chunk-prefix + re-scan + emit.  Each thread owns one (b, chunk, h):
// computes incoming h by scanning the <=31 chunk affines (addresses are
// hc-independent so loads pipeline; only the FMA chain is serial), then
// replays its CL=64 steps from the blocked cv layout (16B = 4 steps/load).
__global__ __launch_bounds__(256) void scan_emit(const h2* __restrict__ cv,
                                                 const float* __restrict__ Ac,
                                                 const float* __restrict__ Bc,
                                                 float* __restrict__ outf,
                                                 ushort* __restrict__ outb,
                                                 const int write_bf16)
{
    int q = blockIdx.x * 256 + threadIdx.x;          // 0 .. B*NC*H-1
    int h = q & (H_-1);
    int c = (q >> 10) & (NC-1);                      // uniform per block
    int b = q >> 15;
    float hc = 0.5f;                                 // h0 = g(0) = 0.5
    for (int cp = 0; cp < c; ++cp) {
        int idx = (b*NC + cp)*H_ + h;
        hc = fmaf(Ac[idx], hc, Bc[idx]);
    }
    const int mb = b*S_ + c*CL;                      // base row (multiple of 4)
    if (write_bf16) {
        #pragma unroll 4
        for (int j = 0; j < 16; ++j) {
            h8 e = *(const h8*)&cv[(((size_t)(mb >> 2) + j)*H_ + h) * 4];
            #pragma unroll
            for (int u = 0; u < 4; ++u) {
                hc = fmaf((float)e[2*u], hc, (float)e[2*u + 1]);
                outb[(size_t)(mb + 4*j + u)*H_ + h] = f2bf(hc);
            }
        }
    } else {
        #pragma unroll 4
        for (int j = 0; j < 16; ++j) {
            h8 e = *(const h8*)&cv[(((size_t)(mb >> 2) + j)*H_ + h) * 4];
            #pragma unroll
            for (int u = 0; u < 4; ++u) {
                hc = fmaf((float)e[2*u], hc, (float)e[2*u + 1]);
                outf[(size_t)(mb + 4*j + u)*H_ + h] = hc;
            }
        }
    }
}

extern "C" void kernel_launch(void* const* d_in, const int* in_sizes, int n_in,
                              void* d_out, int out_size, void* d_ws, size_t ws_size,
                              hipStream_t stream)
{
    const float* x  = (const float*)d_in[0];
    const float* Wz = (const float*)d_in[1];
    const float* bz = (const float*)d_in[2];
    const float* Wh = (const float*)d_in[3];
    const float* bh = (const float*)d_in[4];
    float* out = (float*)d_out;

    static bool attr_set = false;
    if (!attr_set) {
        (void)hipFuncSetAttribute(reinterpret_cast<const void*>(gemm_fused),
                                  hipFuncAttributeMaxDynamicSharedMemorySize, 65536);
        attr_set = true;
    }

    // workspace (~106 MiB)
    ushort* xb  = (ushort*)d_ws;                      // M*D bf16        (32 MiB)
    ushort* wzb = xb  + (size_t)M_*D_;                // L*H*D bf16      (4 MiB)
    ushort* whb = wzb + (size_t)L_*H_*D_;             // L*H*D bf16      (4 MiB)
    h2*     cv  = (h2*)(whb + (size_t)L_*H_*D_);      // M*H fp16x2      (64 MiB)
    float*  Ac  = (float*)(cv + (size_t)M_*H_);       // B*NC*H          (1 MiB)
    float*  Bc  = Ac + B_*NC*H_;

    cast_all<<<(M_*D_/4)/256, 256, 0, stream>>>(x, Wz, Wh, xb, wzb, whb);

    const int gemm_grid = (M_/128) * (H_/64);        // 2048 blocks
    for (int l = 0; l < L_; ++l) {
        gemm_fused<<<gemm_grid, 256, 65536, stream>>>(xb,
                                                      wzb + (size_t)l*H_*D_,
                                                      whb + (size_t)l*H_*D_,
                                                      bz + l*H_, bh + l*H_,
                                                      cv, Ac, Bc);
        scan_emit<<<(B_*NC*H_)/256, 256, 0, stream>>>(cv, Ac, Bc, out, xb,
                                                      (l == 0) ? 1 : 0);
    }
}

// Round 5
// 337.513 us; speedup vs baseline: 1.0180x; 1.0180x over previous
//
#include <hip/hip_runtime.h>
#include <hip/hip_bf16.h>
#include <hip/hip_cooperative_groups.h>

// MinGRU: L=2 layers of  h_t = (1-z_t) h_{t-1} + z_t g(pre_t)
// R8: R7 (cooperative per-layer kernel, cv held in registers across
//     grid.sync) with the occupancy bug fixed: dynamic LDS = exactly 32768 B
//     (R7's 33280 B pushed the occupancy model to 1 block/CU -> cooperative
//     launch of 512 blocks failed silently -> zeros). Plus: host occupancy
//     gate with a compiled-in fallback path (R3-structure gemm + R6 fused
//     scan_emit), and agent-scope atomics for the cross-block Ac/Bc handoff.

#define L_ 2
#define B_ 8
#define S_ 2048
#define D_ 1024
#define H_ 1024
#define M_ (B_*S_)     // 16384
#define NC 32          // chunks per sequence
#define CL (S_/NC)     // 64 steps per chunk

typedef __bf16    bf16x8 __attribute__((ext_vector_type(8)));
typedef float     f32x4  __attribute__((ext_vector_type(4)));
typedef _Float16  h2     __attribute__((ext_vector_type(2)));
typedef _Float16  h8     __attribute__((ext_vector_type(8)));

__device__ __forceinline__ ushort f2bf(float f) {
    union { __hip_bfloat16 h; ushort u; } c;
    c.h = __float2bfloat16(f);   // RNE
    return c.u;
}

__device__ __forceinline__ void async16(const void* g, void* l) {
    __builtin_amdgcn_global_load_lds(
        (const __attribute__((address_space(1))) unsigned int*)g,
        (__attribute__((address_space(3))) unsigned int*)l, 16, 0, 0);
}

// Single fused cast: x (M*D f32->bf16) and, for the low i-range, Wz/Wh too.
__global__ __launch_bounds__(256) void cast_all(const float* __restrict__ x,
                                                const float* __restrict__ Wz,
                                                const float* __restrict__ Wh,
                                                ushort* __restrict__ xb,
                                                ushort* __restrict__ wzb,
                                                ushort* __restrict__ whb) {
    const int nw = L_*H_*D_/4;                       // 524288
    int i = blockIdx.x * 256 + threadIdx.x;          // grid covers M_*D_/4
    {
        float4 v = ((const float4*)x)[i];
        ushort4 o;
        o.x = f2bf(v.x); o.y = f2bf(v.y); o.z = f2bf(v.z); o.w = f2bf(v.w);
        ((ushort4*)xb)[i] = o;
    }
    if (i < nw) {
        float4 v = ((const float4*)Wz)[i];
        ushort4 o;
        o.x = f2bf(v.x); o.y = f2bf(v.y); o.z = f2bf(v.z); o.w = f2bf(v.w);
        ((ushort4*)wzb)[i] = o;
        float4 w = ((const float4*)Wh)[i];
        ushort4 p;
        p.x = f2bf(w.x); p.y = f2bf(w.y); p.z = f2bf(w.z); p.w = f2bf(w.w);
        ((ushort4*)whb)[i] = p;
    }
}

// LDS layout (staging): row R = 64 ushorts (8 chunks of 16B); logical chunk c
// stored at physical chunk c ^ (R&7).  Offset in ushorts:
#define SWZ(R, c) (((R) << 6) + ((((c) ^ ((R) & 7))) << 3))
#define MFMA16 __builtin_amdgcn_mfma_f32_16x16x32_bf16

// ======================= cooperative single-kernel path =====================
// 512 blocks x 256 thr, 2 blocks/CU (launch_bounds(256,2), dyn LDS 32768 B).
// Block -> (b, mgroup, nblk): owns 4 consecutive 128x64 m-tiles (8 chunks).
// Phase A: per tile, R3 GEMM K-loop + epilogue -> cv packed to registers
//          (h8 cvr[4][8] = 128 VGPR), chunk affines Ac/Bc to global (agent
//          atomics).  grid.sync().
// Phase C: per tile, cv regs -> LDS [128][64] h2, 128 threads: chunk prefix
//          from Ac/Bc, 64-step serial replay (bit-identical to R6 scan_emit),
//          coalesced store to out (f32) or xb (bf16 input of layer 1).
__global__ __launch_bounds__(256, 2) void mingru_layer(const ushort* A,
                                                       const ushort* __restrict__ Wz,
                                                       const ushort* __restrict__ Wh,
                                                       const float* __restrict__ bz,
                                                       const float* __restrict__ bh,
                                                       float* Ac,
                                                       float* Bc,
                                                       float* outf,
                                                       ushort* outb,
                                                       int write_bf16)
{
    extern __shared__ __align__(16) ushort sm[];     // 32768 B dynamic

    const int t    = threadIdx.x;
    const int lane = t & 63;
    const int wave = t >> 6;                         // 0..3
    // XCD swizzle: the 16 blocks sharing (b, mgroup) [same A rows] get the
    // same bid&7 -> same XCD L2.  Bijective over 512.
    const int bid  = (int)blockIdx.x;
    const int xcd  = bid & 7;
    const int q8   = bid >> 3;                       // 0..63
    const int nblk = q8 & 15;                        // 0..15
    const int pg   = q8 >> 4;                        // 0..3
    const int panel = pg*8 + xcd;                    // 0..31
    const int b    = panel >> 2;                     // 0..7
    const int mg   = panel & 3;                      // 0..3 (mgroup)
    const int n0 = nblk * 64;
    const int wm = (wave >> 1) * 64;                 // 0 / 64
    const int wn = (wave & 1) * 32;                  // 0 / 32

    const int srow   = lane >> 3;                    // 0..7
    const int scol_g = (((lane & 7) ^ srow) << 3);   // swizzled source chunk
    const int lrow = lane & 15;
    const int lcq  = lane >> 4;                      // 0..3
    const int colq = lane & 15;
    const int rowq = (lane >> 4) << 2;

    // biases are tile-invariant for this block
    float bzv[2], bhv[2];
    #pragma unroll
    for (int nt = 0; nt < 2; ++nt) {
        const int n = n0 + wn + nt*16 + colq;
        bzv[nt] = bz[n];
        bhv[nt] = bh[n];
    }

    h8 cvr[4][8];                                    // [tile][nt*4+mt], 128 VGPR

    // ---------------- Phase A: 4 tiles of GEMM + pack ----------------
    #pragma unroll
    for (int ti = 0; ti < 4; ++ti) {
        const int tloc = mg*4 + ti;                  // m-tile within sequence
        const int m0 = b*S_ + tloc*128;

        f32x4 accz[4][2] = {};
        f32x4 acch[4][2] = {};

        for (int kb = 0; kb < D_; kb += 64) {
            __syncthreads();
            #pragma unroll
            for (int i_ = 0; i_ < 4; ++i_) {         // A: 128 rows
                int r_ = i_*32 + wave*8;
                async16(&A[(size_t)(m0 + r_ + srow)*D_ + kb + scol_g], &sm[r_*64]);
            }
            #pragma unroll
            for (int i_ = 0; i_ < 2; ++i_) {         // Wz, Wh: 64 rows each
                int r_ = i_*32 + wave*8;
                async16(&Wz[(size_t)(n0 + r_ + srow)*D_ + kb + scol_g], &sm[8192  + r_*64]);
                async16(&Wh[(size_t)(n0 + r_ + srow)*D_ + kb + scol_g], &sm[12288 + r_*64]);
            }
            __syncthreads();                         // drains vmcnt -> LDS valid
            #pragma unroll
            for (int kk = 0; kk < 64; kk += 32) {
                const int cq = (kk >> 3) + lcq;      // logical chunk 0..7
                bf16x8 af[4];
                #pragma unroll
                for (int mt = 0; mt < 4; ++mt) {
                    int R = wm + mt*16 + lrow;
                    uint4 u = *(const uint4*)&sm[SWZ(R, cq)];
                    af[mt] = __builtin_bit_cast(bf16x8, u);
                }
                #pragma unroll
                for (int nt = 0; nt < 2; ++nt) {
                    int R = wn + nt*16 + lrow;
                    uint4 uz = *(const uint4*)&sm[8192  + SWZ(R, cq)];
                    uint4 uh = *(const uint4*)&sm[12288 + SWZ(R, cq)];
                    bf16x8 zb = __builtin_bit_cast(bf16x8, uz);
                    bf16x8 hb = __builtin_bit_cast(bf16x8, uh);
                    #pragma unroll
                    for (int mt = 0; mt < 4; ++mt) {
                        accz[mt][nt] = MFMA16(af[mt], zb, accz[mt][nt], 0, 0, 0);
                        acch[mt][nt] = MFMA16(af[mt], hb, acch[mt][nt], 0, 0, 0);
                    }
                }
            }
        }

        __syncthreads();                             // LDS reusable for seg
        float2* seg = (float2*)sm;                   // [32 segs][stride 65]
        #pragma unroll
        for (int nt = 0; nt < 2; ++nt) {
            #pragma unroll
            for (int mt = 0; mt < 4; ++mt) {
                float a = 1.f, bb = 0.f;             // affine over lane's 4 rows
                h8 pk;
                #pragma unroll
                for (int r = 0; r < 4; ++r) {
                    float kx = accz[mt][nt][r] + bzv[nt];
                    float p  = acch[mt][nt][r] + bhv[nt];
                    float e   = __expf(-fabsf(kx));
                    float inv = 1.0f / (1.0f + e);
                    float z   = (kx >= 0.f) ? inv     : e * inv;
                    float c   = (kx >= 0.f) ? e * inv : inv;
                    float g;
                    if (p >= 0.f) g = p + 0.5f;
                    else { float eg = __expf(p); g = eg / (1.0f + eg); }
                    float v = z * g;
                    pk[2*r]     = (_Float16)c;
                    pk[2*r + 1] = (_Float16)v;
                    bb = fmaf(c, bb, v);
                    a *= c;
                }
                cvr[ti][nt*4 + mt] = pk;
                const int sidx = (wm >> 2) + mt*4 + (rowq >> 2);  // 0..31
                seg[sidx*65 + wn + nt*16 + colq] = make_float2(a, bb);
            }
        }
        __syncthreads();
        if (t < 128) {                               // chunk affines
            const int col  = t & 63;
            const int half = t >> 6;
            float a = 1.f, bb = 0.f;
            #pragma unroll
            for (int s = 0; s < 16; ++s) {
                float2 e2 = seg[(half*16 + s)*65 + col];
                bb = fmaf(e2.x, bb, e2.y);
                a *= e2.x;
            }
            const int chunk = tloc*2 + half;
            const int qi = (b*NC + chunk)*H_ + n0 + col;
            __hip_atomic_store(&Ac[qi], a,  __ATOMIC_RELAXED, __HIP_MEMORY_SCOPE_AGENT);
            __hip_atomic_store(&Bc[qi], bb, __ATOMIC_RELAXED, __HIP_MEMORY_SCOPE_AGENT);
        }
    }

    __threadfence();                                 // release Ac/Bc device-wide
    cooperative_groups::this_grid().sync();

    // ---------------- Phase C: scan + emit from register cv ----------------
    h2* cvlds = (h2*)sm;                             // [128 rows][64 cols] h2
    #pragma unroll
    for (int ti = 0; ti < 4; ++ti) {
        const int tloc = mg*4 + ti;
        const int m0 = b*S_ + tloc*128;
        __syncthreads();                             // prev tile's reads done
        #pragma unroll
        for (int nt = 0; nt < 2; ++nt) {
            const int coll = wn + nt*16 + colq;
            #pragma unroll
            for (int mt = 0; mt < 4; ++mt) {
                h8 pk = cvr[ti][nt*4 + mt];
                #pragma unroll
                for (int r = 0; r < 4; ++r) {
                    const int rr = wm + mt*16 + rowq + r;
                    h2 e; e[0] = pk[2*r]; e[1] = pk[2*r + 1];
                    cvlds[rr*64 + coll] = e;
                }
            }
        }
        __syncthreads();
        if (t < 128) {
            const int col = t & 63;
            const int ck  = t >> 6;                  // chunk half 0/1
            const int cg  = tloc*2 + ck;             // global chunk in [0,32)
            float hc = 0.5f;                         // h0 = g(0) = 0.5
            for (int cp = 0; cp < cg; ++cp) {
                int idx = (b*NC + cp)*H_ + n0 + col;
                float av = __hip_atomic_load(&Ac[idx], __ATOMIC_RELAXED, __HIP_MEMORY_SCOPE_AGENT);
                float bv = __hip_atomic_load(&Bc[idx], __ATOMIC_RELAXED, __HIP_MEMORY_SCOPE_AGENT);
                hc = fmaf(av, hc, bv);
            }
            const size_t gbase = (size_t)(m0 + ck*64)*H_ + n0 + col;
            if (write_bf16) {
                #pragma unroll 4
                for (int row = 0; row < 64; ++row) {
                    h2 e = cvlds[(ck*64 + row)*64 + col];
                    hc = fmaf((float)e[0], hc, (float)e[1]);
                    outb[gbase + (size_t)row*H_] = f2bf(hc);
                }
            } else {
                #pragma unroll 4
                for (int row = 0; row < 64; ++row) {
                    h2 e = cvlds[(ck*64 + row)*64 + col];
                    hc = fmaf((float)e[0], hc, (float)e[1]);
                    outf[gbase + (size_t)row*H_] = hc;
                }
            }
        }
    }
}

// =========================== fallback path (R3/R6) ==========================
// R3-structure gemm (proven 87.8 us) with the h8 blocked cv epilogue.
__global__ __launch_bounds__(256) void gemm_fb(const ushort* __restrict__ A,
                                               const ushort* __restrict__ Wz,
                                               const ushort* __restrict__ Wh,
                                               const float* __restrict__ bz,
                                               const float* __restrict__ bh,
                                               h2* __restrict__ cv,
                                               float* __restrict__ Ac,
                                               float* __restrict__ Bc)
{
    __shared__ __align__(16) ushort sm[16384];       // 32 KiB

    const int t    = threadIdx.x;
    const int lane = t & 63;
    const int wave = t >> 6;
    const int xcd = (int)blockIdx.x & 7;
    const int k8  = (int)blockIdx.x >> 3;            // 0..255
    const int nblk = k8 & 15;
    const int mblk = ((k8 >> 4) << 3) + xcd;         // 0..127
    const int m0 = mblk * 128;
    const int n0 = nblk * 64;
    const int wm = (wave >> 1) * 64;
    const int wn = (wave & 1) * 32;

    const int srow   = lane >> 3;
    const int scol_g = (((lane & 7) ^ srow) << 3);

    f32x4 accz[4][2] = {};
    f32x4 acch[4][2] = {};
    const int lrow = lane & 15;
    const int lcq  = lane >> 4;

    for (int kb = 0; kb < D_; kb += 64) {
        __syncthreads();
        #pragma unroll
        for (int i = 0; i < 4; ++i) {
            int r = i*32 + wave*8;
            async16(&A[(size_t)(m0 + r + srow)*D_ + kb + scol_g], &sm[r*64]);
        }
        #pragma unroll
        for (int i = 0; i < 2; ++i) {
            int r = i*32 + wave*8;
            async16(&Wz[(size_t)(n0 + r + srow)*D_ + kb + scol_g], &sm[8192  + r*64]);
            async16(&Wh[(size_t)(n0 + r + srow)*D_ + kb + scol_g], &sm[12288 + r*64]);
        }
        __syncthreads();
        #pragma unroll
        for (int kk = 0; kk < 64; kk += 32) {
            const int cq = (kk >> 3) + lcq;
            bf16x8 af[4];
            #pragma unroll
            for (int mt = 0; mt < 4; ++mt) {
                int R = wm + mt*16 + lrow;
                uint4 u = *(const uint4*)&sm[SWZ(R, cq)];
                af[mt] = __builtin_bit_cast(bf16x8, u);
            }
            #pragma unroll
            for (int nt = 0; nt < 2; ++nt) {
                int R = wn + nt*16 + lrow;
                uint4 uz = *(const uint4*)&sm[8192  + SWZ(R, cq)];
                uint4 uh = *(const uint4*)&sm[12288 + SWZ(R, cq)];
                bf16x8 zb = __builtin_bit_cast(bf16x8, uz);
                bf16x8 hb = __builtin_bit_cast(bf16x8, uh);
                #pragma unroll
                for (int mt = 0; mt < 4; ++mt) {
                    accz[mt][nt] = MFMA16(af[mt], zb, accz[mt][nt], 0, 0, 0);
                    acch[mt][nt] = MFMA16(af[mt], hb, acch[mt][nt], 0, 0, 0);
                }
            }
        }
    }

    __syncthreads();
    float2* seg = (float2*)sm;
    const int colq = lane & 15;
    const int rowq = (lane >> 4) << 2;
    #pragma unroll
    for (int nt = 0; nt < 2; ++nt) {
        const int n = n0 + wn + nt*16 + colq;
        const float bzv = bz[n];
        const float bhv = bh[n];
        #pragma unroll
        for (int mt = 0; mt < 4; ++mt) {
            float a = 1.f, bb = 0.f;
            h8 pk;
            #pragma unroll
            for (int r = 0; r < 4; ++r) {
                float kx = accz[mt][nt][r] + bzv;
                float p  = acch[mt][nt][r] + bhv;
                float e   = __expf(-fabsf(kx));
                float inv = 1.0f / (1.0f + e);
                float z   = (kx >= 0.f) ? inv     : e * inv;
                float c   = (kx >= 0.f) ? e * inv : inv;
                float g;
                if (p >= 0.f) g = p + 0.5f;
                else { float eg = __expf(p); g = eg / (1.0f + eg); }
                float v = z * g;
                pk[2*r]     = (_Float16)c;
                pk[2*r + 1] = (_Float16)v;
                bb = fmaf(c, bb, v);
                a *= c;
            }
            const int mb4 = (m0 + wm + mt*16 + rowq) >> 2;
            *(h8*)&cv[((size_t)mb4 * H_ + n) * 4] = pk;
            const int sidx = (wm >> 2) + mt*4 + (rowq >> 2);
            seg[sidx*65 + wn + nt*16 + colq] = make_float2(a, bb);
        }
    }
    __syncthreads();
    if (t < 128) {
        const int col  = t & 63;
        const int half = t >> 6;
        float a = 1.f, bb = 0.f;
        #pragma unroll
        for (int s = 0; s < 16; ++s) {
            float2 e2 = seg[(half*16 + s)*65 + col];
            bb = fmaf(e2.x, bb, e2.y);
            a *= e2.x;
        }
        const int b     = m0 >> 11;
        const int chunk = ((m0 >> 6) & (NC - 1)) + half;
        const int q = (b*NC + chunk)*H_ + n0 + col;
        Ac[q] = a; Bc[q] = bb;
    }
}

// Fused chunk-prefix + re-scan + emit (R6, passing).
__global__ __launch_bounds__(256) void scan_emit_fb(const h2* __restrict__ cv,
                                                    const float* __restrict__ Ac,
                                                    const float* __restrict__ Bc,
                                                    float* __restrict__ outf,
                                                    ushort* __restrict__ outb,
                                                    const int write_bf16)
{
    int q = blockIdx.x * 256 + threadIdx.x;          // 0 .. B*NC*H-1
    int h = q & (H_-1);
    int c = (q >> 10) & (NC-1);
    int b = q >> 15;
    float hc = 0.5f;
    for (int cp = 0; cp < c; ++cp) {
        int idx = (b*NC + cp)*H_ + h;
        hc = fmaf(Ac[idx], hc, Bc[idx]);
    }
    const int mb = b*S_ + c*CL;
    if (write_bf16) {
        #pragma unroll 4
        for (int j = 0; j < 16; ++j) {
            h8 e = *(const h8*)&cv[(((size_t)(mb >> 2) + j)*H_ + h) * 4];
            #pragma unroll
            for (int u = 0; u < 4; ++u) {
                hc = fmaf((float)e[2*u], hc, (float)e[2*u + 1]);
                outb[(size_t)(mb + 4*j + u)*H_ + h] = f2bf(hc);
            }
        }
    } else {
        #pragma unroll 4
        for (int j = 0; j < 16; ++j) {
            h8 e = *(const h8*)&cv[(((size_t)(mb >> 2) + j)*H_ + h) * 4];
            #pragma unroll
            for (int u = 0; u < 4; ++u) {
                hc = fmaf((float)e[2*u], hc, (float)e[2*u + 1]);
                outf[(size_t)(mb + 4*j + u)*H_ + h] = hc;
            }
        }
    }
}

extern "C" void kernel_launch(void* const* d_in, const int* in_sizes, int n_in,
                              void* d_out, int out_size, void* d_ws, size_t ws_size,
                              hipStream_t stream)
{
    const float* x  = (const float*)d_in[0];
    const float* Wz = (const float*)d_in[1];
    const float* bz = (const float*)d_in[2];
    const float* Wh = (const float*)d_in[3];
    const float* bh = (const float*)d_in[4];
    float* out = (float*)d_out;

    // workspace (~107 MiB; cv used only on the fallback path)
    ushort* xb  = (ushort*)d_ws;                      // M*D bf16        (32 MiB)
    ushort* wzb = xb  + (size_t)M_*D_;                // L*H*D bf16      (4 MiB)
    ushort* whb = wzb + (size_t)L_*H_*D_;             // L*H*D bf16      (4 MiB)
    h2*     cv  = (h2*)(whb + (size_t)L_*H_*D_);      // M*H fp16x2      (64 MiB)
    float*  Ac  = (float*)(cv + (size_t)M_*H_);       // B*NC*H          (1 MiB)
    float*  Bc  = Ac + B_*NC*H_;

    // capture-safe one-time occupancy gate for the cooperative path
    static int coop_ok = -1;
    if (coop_ok < 0) {
        int nb = 0;
        hipError_t e = hipOccupancyMaxActiveBlocksPerMultiprocessor(
            &nb, reinterpret_cast<const void*>(mingru_layer), 256, (size_t)32768);
        coop_ok = (e == hipSuccess && nb >= 2) ? 1 : 0;
    }

    cast_all<<<(M_*D_/4)/256, 256, 0, stream>>>(x, Wz, Wh, xb, wzb, whb);

    if (coop_ok) {
        for (int l = 0; l < L_; ++l) {
            const ushort* A_  = xb;
            const ushort* Wz_ = wzb + (size_t)l*H_*D_;
            const ushort* Wh_ = whb + (size_t)l*H_*D_;
            const float*  bz_ = bz + l*H_;
            const float*  bh_ = bh + l*H_;
            float*  Ac_ = Ac;
            float*  Bc_ = Bc;
            float*  of_ = out;
            ushort* ob_ = xb;
            int wb = (l == 0) ? 1 : 0;
            void* args[] = {&A_, &Wz_, &Wh_, &bz_, &bh_, &Ac_, &Bc_, &of_, &ob_, &wb};
            hipLaunchCooperativeKernel(reinterpret_cast<const void*>(mingru_layer),
                                       dim3(512), dim3(256), args, 32768, stream);
        }
    } else {
        const int gemm_grid = (M_/128) * (H_/64);    // 2048 blocks
        for (int l = 0; l < L_; ++l) {
            gemm_fb<<<gemm_grid, 256, 0, stream>>>(xb,
                                                   wzb + (size_t)l*H_*D_,
                                                   whb + (size_t)l*H_*D_,
                                                   bz + l*H_, bh + l*H_,
                                                   cv, Ac, Bc);
            scan_emit_fb<<<(B_*NC*H_)/256, 256, 0, stream>>>(cv, Ac, Bc, out, xb,
                                                             (l == 0) ? 1 : 0);
        }
    }
}

// Round 6
// 333.566 us; speedup vs baseline: 1.0301x; 1.0118x over previous
//
#include <hip/hip_runtime.h>
#include <hip/hip_bf16.h>
#include <hip/hip_cooperative_groups.h>

// MinGRU: L=2 layers of  h_t = (1-z_t) h_{t-1} + z_t g(pre_t)
// R9: cooperative per-layer kernel WITHOUT register-carried cv (R8's cvr[4][8]
//     spilled to scratch: VGPR=128 < needed, +67MB WRITE / +53MB FETCH of
//     spill traffic, MfmaUtil 12.8). Phase A = verbatim R3 GEMM (87.8 us
//     proven) x4 tiles/block, cv via HBM (h8 blocked, coalesced). grid.sync.
//     Phase C = verbatim R6 fused scan_emit, 2 items/thread. The coop fusion
//     only removes the ~70-95 us of inter-dispatch gaps. Fallback path kept.

#define L_ 2
#define B_ 8
#define S_ 2048
#define D_ 1024
#define H_ 1024
#define M_ (B_*S_)     // 16384
#define NC 32          // chunks per sequence
#define CL (S_/NC)     // 64 steps per chunk

typedef __bf16    bf16x8 __attribute__((ext_vector_type(8)));
typedef float     f32x4  __attribute__((ext_vector_type(4)));
typedef _Float16  h2     __attribute__((ext_vector_type(2)));
typedef _Float16  h8     __attribute__((ext_vector_type(8)));

__device__ __forceinline__ ushort f2bf(float f) {
    union { __hip_bfloat16 h; ushort u; } c;
    c.h = __float2bfloat16(f);   // RNE
    return c.u;
}

__device__ __forceinline__ void async16(const void* g, void* l) {
    __builtin_amdgcn_global_load_lds(
        (const __attribute__((address_space(1))) unsigned int*)g,
        (__attribute__((address_space(3))) unsigned int*)l, 16, 0, 0);
}

// Single fused cast: x (M*D f32->bf16) and, for the low i-range, Wz/Wh too.
__global__ __launch_bounds__(256) void cast_all(const float* __restrict__ x,
                                                const float* __restrict__ Wz,
                                                const float* __restrict__ Wh,
                                                ushort* __restrict__ xb,
                                                ushort* __restrict__ wzb,
                                                ushort* __restrict__ whb) {
    const int nw = L_*H_*D_/4;                       // 524288
    int i = blockIdx.x * 256 + threadIdx.x;          // grid covers M_*D_/4
    {
        float4 v = ((const float4*)x)[i];
        ushort4 o;
        o.x = f2bf(v.x); o.y = f2bf(v.y); o.z = f2bf(v.z); o.w = f2bf(v.w);
        ((ushort4*)xb)[i] = o;
    }
    if (i < nw) {
        float4 v = ((const float4*)Wz)[i];
        ushort4 o;
        o.x = f2bf(v.x); o.y = f2bf(v.y); o.z = f2bf(v.z); o.w = f2bf(v.w);
        ((ushort4*)wzb)[i] = o;
        float4 w = ((const float4*)Wh)[i];
        ushort4 p;
        p.x = f2bf(w.x); p.y = f2bf(w.y); p.z = f2bf(w.z); p.w = f2bf(w.w);
        ((ushort4*)whb)[i] = p;
    }
}

// LDS layout (staging): row R = 64 ushorts (8 chunks of 16B); logical chunk c
// stored at physical chunk c ^ (R&7).  Offset in ushorts:
#define SWZ(R, c) (((R) << 6) + ((((c) ^ ((R) & 7))) << 3))
#define MFMA16 __builtin_amdgcn_mfma_f32_16x16x32_bf16

// ======================= cooperative single-kernel path =====================
// 512 blocks x 256 thr, 2 blocks/CU (static LDS 32 KiB, launch_bounds(256,2)).
// Phase A: rep=0..3, bid2 = blockIdx + rep*512 -> R3's exact tile mapping and
//          K-loop; epilogue writes cv (h8 blocked) + chunk affines Ac/Bc.
// grid.sync()  (device-scope acq/rel fences make cv/Ac/Bc visible)
// Phase C: q = blockIdx*256+tid (+131072): R6's fused chunk-prefix + replay
//          + emit (bit-identical math to R6).
__global__ __launch_bounds__(256, 2) void mingru_layer(const ushort* A,
                                                       const ushort* __restrict__ Wz,
                                                       const ushort* __restrict__ Wh,
                                                       const float* __restrict__ bz,
                                                       const float* __restrict__ bh,
                                                       h2* __restrict__ cv,
                                                       float* Ac,
                                                       float* Bc,
                                                       float* outf,
                                                       ushort* outb,
                                                       int write_bf16)
{
    __shared__ __align__(16) ushort sm[16384];       // 32 KiB static

    const int t    = threadIdx.x;
    const int lane = t & 63;
    const int wave = t >> 6;                         // 0..3
    const int lrow = lane & 15;
    const int lcq  = lane >> 4;                      // 0..3
    const int srow   = lane >> 3;                    // 0..7
    const int scol_g = (((lane & 7) ^ srow) << 3);   // swizzled source chunk
    const int colq = lane & 15;
    const int rowq = (lane >> 4) << 2;
    const int wm = (wave >> 1) * 64;                 // 0 / 64
    const int wn = (wave & 1) * 32;                  // 0 / 32

    // ---------------- Phase A: 4 reps of the R3 GEMM ----------------
    for (int rep = 0; rep < 4; ++rep) {
        const int bid2 = (int)blockIdx.x + (rep << 9);
        const int xcd = bid2 & 7;
        const int k8  = bid2 >> 3;                   // 0..255
        const int nblk = k8 & 15;
        const int mblk = ((k8 >> 4) << 3) + xcd;     // 0..127
        const int m0 = mblk * 128;
        const int n0 = nblk * 64;

        f32x4 accz[4][2] = {};
        f32x4 acch[4][2] = {};

        for (int kb = 0; kb < D_; kb += 64) {
            __syncthreads();
            #pragma unroll
            for (int i = 0; i < 4; ++i) {            // A: 128 rows
                int r = i*32 + wave*8;
                async16(&A[(size_t)(m0 + r + srow)*D_ + kb + scol_g], &sm[r*64]);
            }
            #pragma unroll
            for (int i = 0; i < 2; ++i) {            // Wz, Wh: 64 rows each
                int r = i*32 + wave*8;
                async16(&Wz[(size_t)(n0 + r + srow)*D_ + kb + scol_g], &sm[8192  + r*64]);
                async16(&Wh[(size_t)(n0 + r + srow)*D_ + kb + scol_g], &sm[12288 + r*64]);
            }
            __syncthreads();                         // drains vmcnt -> LDS valid
            #pragma unroll
            for (int kk = 0; kk < 64; kk += 32) {
                const int cq = (kk >> 3) + lcq;      // logical chunk 0..7
                bf16x8 af[4];
                #pragma unroll
                for (int mt = 0; mt < 4; ++mt) {
                    int R = wm + mt*16 + lrow;
                    uint4 u = *(const uint4*)&sm[SWZ(R, cq)];
                    af[mt] = __builtin_bit_cast(bf16x8, u);
                }
                #pragma unroll
                for (int nt = 0; nt < 2; ++nt) {
                    int R = wn + nt*16 + lrow;
                    uint4 uz = *(const uint4*)&sm[8192  + SWZ(R, cq)];
                    uint4 uh = *(const uint4*)&sm[12288 + SWZ(R, cq)];
                    bf16x8 zb = __builtin_bit_cast(bf16x8, uz);
                    bf16x8 hb = __builtin_bit_cast(bf16x8, uh);
                    #pragma unroll
                    for (int mt = 0; mt < 4; ++mt) {
                        accz[mt][nt] = MFMA16(af[mt], zb, accz[mt][nt], 0, 0, 0);
                        acch[mt][nt] = MFMA16(af[mt], hb, acch[mt][nt], 0, 0, 0);
                    }
                }
            }
        }

        __syncthreads();                             // MFMA LDS reads done
        float2* seg = (float2*)sm;                   // [32 segs][stride 65]
        #pragma unroll
        for (int nt = 0; nt < 2; ++nt) {
            const int n = n0 + wn + nt*16 + colq;
            const float bzv = bz[n];
            const float bhv = bh[n];
            #pragma unroll
            for (int mt = 0; mt < 4; ++mt) {
                float a = 1.f, bb = 0.f;             // affine over lane's 4 rows
                h8 pk;
                #pragma unroll
                for (int r = 0; r < 4; ++r) {
                    float kx = accz[mt][nt][r] + bzv;
                    float p  = acch[mt][nt][r] + bhv;
                    float e   = __expf(-fabsf(kx));
                    float inv = 1.0f / (1.0f + e);
                    float z   = (kx >= 0.f) ? inv     : e * inv;
                    float c   = (kx >= 0.f) ? e * inv : inv;
                    float g;
                    if (p >= 0.f) g = p + 0.5f;
                    else { float eg = __expf(p); g = eg / (1.0f + eg); }
                    float v = z * g;
                    pk[2*r]     = (_Float16)c;
                    pk[2*r + 1] = (_Float16)v;
                    bb = fmaf(c, bb, v);
                    a *= c;
                }
                const int mb4 = (m0 + wm + mt*16 + rowq) >> 2;   // m&3 == r
                *(h8*)&cv[((size_t)mb4 * H_ + n) * 4] = pk;      // 16B coalesced
                const int sidx = (wm >> 2) + mt*4 + (rowq >> 2); // 0..31
                seg[sidx*65 + wn + nt*16 + colq] = make_float2(a, bb);
            }
        }
        __syncthreads();
        if (t < 128) {                               // chunk affines
            const int col  = t & 63;
            const int half = t >> 6;
            float a = 1.f, bb = 0.f;
            #pragma unroll
            for (int s = 0; s < 16; ++s) {
                float2 e2 = seg[(half*16 + s)*65 + col];
                bb = fmaf(e2.x, bb, e2.y);
                a *= e2.x;
            }
            const int b     = m0 >> 11;              // S = 2048
            const int chunk = ((m0 >> 6) & (NC - 1)) + half;
            const int qi = (b*NC + chunk)*H_ + n0 + col;
            Ac[qi] = a; Bc[qi] = bb;
        }
        // next rep's K-loop starts with __syncthreads -> seg reads complete
    }

    __threadfence();                                 // release cv/Ac/Bc
    cooperative_groups::this_grid().sync();

    // ---------------- Phase C: fused chunk-prefix + replay + emit ----------
    #pragma unroll
    for (int rep = 0; rep < 2; ++rep) {
        const int q = (int)blockIdx.x * 256 + t + rep * 131072;  // 0..262143
        const int h = q & (H_-1);
        const int c = (q >> 10) & (NC-1);
        const int b = q >> 15;
        float hc = 0.5f;                             // h0 = g(0) = 0.5
        for (int cp = 0; cp < c; ++cp) {
            int idx = (b*NC + cp)*H_ + h;
            hc = fmaf(Ac[idx], hc, Bc[idx]);
        }
        const int mb = b*S_ + c*CL;                  // base row (multiple of 4)
        if (write_bf16) {
            #pragma unroll 4
            for (int j = 0; j < 16; ++j) {
                h8 e = *(const h8*)&cv[(((size_t)(mb >> 2) + j)*H_ + h) * 4];
                #pragma unroll
                for (int u = 0; u < 4; ++u) {
                    hc = fmaf((float)e[2*u], hc, (float)e[2*u + 1]);
                    outb[(size_t)(mb + 4*j + u)*H_ + h] = f2bf(hc);
                }
            }
        } else {
            #pragma unroll 4
            for (int j = 0; j < 16; ++j) {
                h8 e = *(const h8*)&cv[(((size_t)(mb >> 2) + j)*H_ + h) * 4];
                #pragma unroll
                for (int u = 0; u < 4; ++u) {
                    hc = fmaf((float)e[2*u], hc, (float)e[2*u + 1]);
                    outf[(size_t)(mb + 4*j + u)*H_ + h] = hc;
                }
            }
        }
    }
}

// =========================== fallback path (R3/R6) ==========================
__global__ __launch_bounds__(256) void gemm_fb(const ushort* __restrict__ A,
                                               const ushort* __restrict__ Wz,
                                               const ushort* __restrict__ Wh,
                                               const float* __restrict__ bz,
                                               const float* __restrict__ bh,
                                               h2* __restrict__ cv,
                                               float* __restrict__ Ac,
                                               float* __restrict__ Bc)
{
    __shared__ __align__(16) ushort sm[16384];       // 32 KiB

    const int t    = threadIdx.x;
    const int lane = t & 63;
    const int wave = t >> 6;
    const int xcd = (int)blockIdx.x & 7;
    const int k8  = (int)blockIdx.x >> 3;            // 0..255
    const int nblk = k8 & 15;
    const int mblk = ((k8 >> 4) << 3) + xcd;         // 0..127
    const int m0 = mblk * 128;
    const int n0 = nblk * 64;
    const int wm = (wave >> 1) * 64;
    const int wn = (wave & 1) * 32;

    const int srow   = lane >> 3;
    const int scol_g = (((lane & 7) ^ srow) << 3);

    f32x4 accz[4][2] = {};
    f32x4 acch[4][2] = {};
    const int lrow = lane & 15;
    const int lcq  = lane >> 4;

    for (int kb = 0; kb < D_; kb += 64) {
        __syncthreads();
        #pragma unroll
        for (int i = 0; i < 4; ++i) {
            int r = i*32 + wave*8;
            async16(&A[(size_t)(m0 + r + srow)*D_ + kb + scol_g], &sm[r*64]);
        }
        #pragma unroll
        for (int i = 0; i < 2; ++i) {
            int r = i*32 + wave*8;
            async16(&Wz[(size_t)(n0 + r + srow)*D_ + kb + scol_g], &sm[8192  + r*64]);
            async16(&Wh[(size_t)(n0 + r + srow)*D_ + kb + scol_g], &sm[12288 + r*64]);
        }
        __syncthreads();
        #pragma unroll
        for (int kk = 0; kk < 64; kk += 32) {
            const int cq = (kk >> 3) + lcq;
            bf16x8 af[4];
            #pragma unroll
            for (int mt = 0; mt < 4; ++mt) {
                int R = wm + mt*16 + lrow;
                uint4 u = *(const uint4*)&sm[SWZ(R, cq)];
                af[mt] = __builtin_bit_cast(bf16x8, u);
            }
            #pragma unroll
            for (int nt = 0; nt < 2; ++nt) {
                int R = wn + nt*16 + lrow;
                uint4 uz = *(const uint4*)&sm[8192  + SWZ(R, cq)];
                uint4 uh = *(const uint4*)&sm[12288 + SWZ(R, cq)];
                bf16x8 zb = __builtin_bit_cast(bf16x8, uz);
                bf16x8 hb = __builtin_bit_cast(bf16x8, uh);
                #pragma unroll
                for (int mt = 0; mt < 4; ++mt) {
                    accz[mt][nt] = MFMA16(af[mt], zb, accz[mt][nt], 0, 0, 0);
                    acch[mt][nt] = MFMA16(af[mt], hb, acch[mt][nt], 0, 0, 0);
                }
            }
        }
    }

    __syncthreads();
    float2* seg = (float2*)sm;
    const int colq = lane & 15;
    const int rowq = (lane >> 4) << 2;
    #pragma unroll
    for (int nt = 0; nt < 2; ++nt) {
        const int n = n0 + wn + nt*16 + colq;
        const float bzv = bz[n];
        const float bhv = bh[n];
        #pragma unroll
        for (int mt = 0; mt < 4; ++mt) {
            float a = 1.f, bb = 0.f;
            h8 pk;
            #pragma unroll
            for (int r = 0; r < 4; ++r) {
                float kx = accz[mt][nt][r] + bzv;
                float p  = acch[mt][nt][r] + bhv;
                float e   = __expf(-fabsf(kx));
                float inv = 1.0f / (1.0f + e);
                float z   = (kx >= 0.f) ? inv     : e * inv;
                float c   = (kx >= 0.f) ? e * inv : inv;
                float g;
                if (p >= 0.f) g = p + 0.5f;
                else { float eg = __expf(p); g = eg / (1.0f + eg); }
                float v = z * g;
                pk[2*r]     = (_Float16)c;
                pk[2*r + 1] = (_Float16)v;
                bb = fmaf(c, bb, v);
                a *= c;
            }
            const int mb4 = (m0 + wm + mt*16 + rowq) >> 2;
            *(h8*)&cv[((size_t)mb4 * H_ + n) * 4] = pk;
            const int sidx = (wm >> 2) + mt*4 + (rowq >> 2);
            seg[sidx*65 + wn + nt*16 + colq] = make_float2(a, bb);
        }
    }
    __syncthreads();
    if (t < 128) {
        const int col  = t & 63;
        const int half = t >> 6;
        float a = 1.f, bb = 0.f;
        #pragma unroll
        for (int s = 0; s < 16; ++s) {
            float2 e2 = seg[(half*16 + s)*65 + col];
            bb = fmaf(e2.x, bb, e2.y);
            a *= e2.x;
        }
        const int b     = m0 >> 11;
        const int chunk = ((m0 >> 6) & (NC - 1)) + half;
        const int q = (b*NC + chunk)*H_ + n0 + col;
        Ac[q] = a; Bc[q] = bb;
    }
}

__global__ __launch_bounds__(256) void scan_emit_fb(const h2* __restrict__ cv,
                                                    const float* __restrict__ Ac,
                                                    const float* __restrict__ Bc,
                                                    float* __restrict__ outf,
                                                    ushort* __restrict__ outb,
                                                    const int write_bf16)
{
    int q = blockIdx.x * 256 + threadIdx.x;          // 0 .. B*NC*H-1
    int h = q & (H_-1);
    int c = (q >> 10) & (NC-1);
    int b = q >> 15;
    float hc = 0.5f;
    for (int cp = 0; cp < c; ++cp) {
        int idx = (b*NC + cp)*H_ + h;
        hc = fmaf(Ac[idx], hc, Bc[idx]);
    }
    const int mb = b*S_ + c*CL;
    if (write_bf16) {
        #pragma unroll 4
        for (int j = 0; j < 16; ++j) {
            h8 e = *(const h8*)&cv[(((size_t)(mb >> 2) + j)*H_ + h) * 4];
            #pragma unroll
            for (int u = 0; u < 4; ++u) {
                hc = fmaf((float)e[2*u], hc, (float)e[2*u + 1]);
                outb[(size_t)(mb + 4*j + u)*H_ + h] = f2bf(hc);
            }
        }
    } else {
        #pragma unroll 4
        for (int j = 0; j < 16; ++j) {
            h8 e = *(const h8*)&cv[(((size_t)(mb >> 2) + j)*H_ + h) * 4];
            #pragma unroll
            for (int u = 0; u < 4; ++u) {
                hc = fmaf((float)e[2*u], hc, (float)e[2*u + 1]);
                outf[(size_t)(mb + 4*j + u)*H_ + h] = hc;
            }
        }
    }
}

extern "C" void kernel_launch(void* const* d_in, const int* in_sizes, int n_in,
                              void* d_out, int out_size, void* d_ws, size_t ws_size,
                              hipStream_t stream)
{
    const float* x  = (const float*)d_in[0];
    const float* Wz = (const float*)d_in[1];
    const float* bz = (const float*)d_in[2];
    const float* Wh = (const float*)d_in[3];
    const float* bh = (const float*)d_in[4];
    float* out = (float*)d_out;

    // workspace (~107 MiB)
    ushort* xb  = (ushort*)d_ws;                      // M*D bf16        (32 MiB)
    ushort* wzb = xb  + (size_t)M_*D_;                // L*H*D bf16      (4 MiB)
    ushort* whb = wzb + (size_t)L_*H_*D_;             // L*H*D bf16      (4 MiB)
    h2*     cv  = (h2*)(whb + (size_t)L_*H_*D_);      // M*H fp16x2      (64 MiB)
    float*  Ac  = (float*)(cv + (size_t)M_*H_);       // B*NC*H          (1 MiB)
    float*  Bc  = Ac + B_*NC*H_;

    // capture-safe one-time occupancy gate for the cooperative path
    static int coop_ok = -1;
    if (coop_ok < 0) {
        int nb = 0;
        hipError_t e = hipOccupancyMaxActiveBlocksPerMultiprocessor(
            &nb, reinterpret_cast<const void*>(mingru_layer), 256, (size_t)0);
        coop_ok = (e == hipSuccess && nb >= 2) ? 1 : 0;
    }

    cast_all<<<(M_*D_/4)/256, 256, 0, stream>>>(x, Wz, Wh, xb, wzb, whb);

    if (coop_ok) {
        for (int l = 0; l < L_; ++l) {
            const ushort* A_  = xb;
            const ushort* Wz_ = wzb + (size_t)l*H_*D_;
            const ushort* Wh_ = whb + (size_t)l*H_*D_;
            const float*  bz_ = bz + l*H_;
            const float*  bh_ = bh + l*H_;
            h2*     cv_ = cv;
            float*  Ac_ = Ac;
            float*  Bc_ = Bc;
            float*  of_ = out;
            ushort* ob_ = xb;
            int wb = (l == 0) ? 1 : 0;
            void* args[] = {&A_, &Wz_, &Wh_, &bz_, &bh_, &cv_, &Ac_, &Bc_,
                            &of_, &ob_, &wb};
            hipLaunchCooperativeKernel(reinterpret_cast<const void*>(mingru_layer),
                                       dim3(512), dim3(256), args, 0, stream);
        }
    } else {
        const int gemm_grid = (M_/128) * (H_/64);    // 2048 blocks
        for (int l = 0; l < L_; ++l) {
            gemm_fb<<<gemm_grid, 256, 0, stream>>>(xb,
                                                   wzb + (size_t)l*H_*D_,
                                                   whb + (size_t)l*H_*D_,
                                                   bz + l*H_, bh + l*H_,
                                                   cv, Ac, Bc);
            scan_emit_fb<<<(B_*NC*H_)/256, 256, 0, stream>>>(cv, Ac, Bc, out, xb,
                                                             (l == 0) ? 1 : 0);
        }
    }
}